// Round 1
// baseline (1911.305 us; speedup 1.0000x reference)
//
#include <hip/hip_runtime.h>

// KG attention, 3 hops. Key simplifications vs reference:
//  - softmax denom & cnt divide cancel under L2 normalize: agg_next = normalize(sum_e exp(att-m)*X_e)
//  - qh = agg @ q_w computed per NODE (not per edge)
//  - CSR by head built once per call -> gather aggregation, no float atomics
// Precision: k_w/q_w/qh in bf16 (threshold 0.325 is bf16-scale), accumulation f32.

#define DD 128

typedef unsigned short u16;
typedef unsigned int u32;

__device__ __forceinline__ float bf2f(u16 u) { return __uint_as_float(((u32)u) << 16); }
__device__ __forceinline__ u16 f2bf(float f) {
    u32 u = __float_as_uint(f);
    u += 0x7FFFu + ((u >> 16) & 1u);   // RNE
    return (u16)(u >> 16);
}
__device__ __forceinline__ float fast_tanh(float x) {
    float a = fabsf(x);
    float e = __expf(2.f * fminf(a, 20.f));   // clamp: avoid inf/inf
    float t = 1.f - 2.f / (e + 1.f);
    return copysignf(t, x);
}

// ------------------- CSR build (once per call; head is hop-invariant) -------------------
__global__ void k_hist(const int* __restrict__ head, int E, int* __restrict__ counts) {
    int e = blockIdx.x * blockDim.x + threadIdx.x;
    if (e < E) atomicAdd(&counts[head[e]], 1);
}

__global__ void k_scan_a(const int* __restrict__ counts, int N, int* __restrict__ row_off,
                         int* __restrict__ partials) {
    __shared__ int sw[16];
    int i = blockIdx.x * 1024 + threadIdx.x;
    int v = (i < N) ? counts[i] : 0;
    int lane = threadIdx.x & 63, wid = threadIdx.x >> 6;
    int x = v;
    #pragma unroll
    for (int off = 1; off < 64; off <<= 1) {
        int t = __shfl_up(x, off);
        if (lane >= off) x += t;
    }
    if (lane == 63) sw[wid] = x;
    __syncthreads();
    if (threadIdx.x == 0) {
        int run = 0;
        for (int w0 = 0; w0 < 16; w0++) { int t = sw[w0]; sw[w0] = run; run += t; }
        partials[blockIdx.x] = run;
    }
    __syncthreads();
    if (i < N) row_off[i] = x - v + sw[wid];   // chunk-local exclusive
}
__global__ void k_scan_b(int* __restrict__ partials, int nch) {
    if (blockIdx.x == 0 && threadIdx.x == 0) {
        int run = 0;
        for (int c = 0; c < nch; c++) { int t = partials[c]; partials[c] = run; run += t; }
    }
}
__global__ void k_scan_c(int* __restrict__ row_off, const int* __restrict__ partials, int N, int E) {
    int i = blockIdx.x * 1024 + threadIdx.x;
    if (i < N) row_off[i] += partials[blockIdx.x];
    if (i == 0) row_off[N] = E;
}
__global__ void k_fill(const int* __restrict__ head, const int* __restrict__ tail,
                       const int* __restrict__ etype, int E, const int* __restrict__ row_off,
                       int* __restrict__ cursor, int* __restrict__ c_eid,
                       int* __restrict__ c_tail, int* __restrict__ c_type) {
    int e = blockIdx.x * blockDim.x + threadIdx.x;
    if (e >= E) return;
    int h = head[e];
    int p = row_off[h] + atomicAdd(&cursor[h], 1);
    c_eid[p] = e; c_tail[p] = tail[e]; c_type[p] = etype[e];
}

// ------------------- qh = agg @ q_w  (bf16 out), 8-node register tile -------------------
__global__ void __launch_bounds__(128) k_qproj(const float* __restrict__ agg,
                                               const float* __restrict__ qw,
                                               u16* __restrict__ qh, int N) {
    __shared__ u16 qwb[DD * DD];       // [j][d] bf16, 32 KB
    __shared__ float rows[8][DD];      // 8 staged agg rows, 4 KB
    for (int i = threadIdx.x; i < DD * DD; i += 128) qwb[i] = f2bf(qw[i]);
    __syncthreads();
    int nch = (N + 7) / 8;
    for (int c = blockIdx.x; c < nch; c += gridDim.x) {
        int base = c * 8;
        for (int t = threadIdx.x; t < 8 * DD; t += 128) {
            int idx = base * DD + t;
            rows[t >> 7][t & 127] = (idx < N * DD) ? agg[idx] : 0.f;
        }
        __syncthreads();
        int d = threadIdx.x;
        float acc[8] = {0.f, 0.f, 0.f, 0.f, 0.f, 0.f, 0.f, 0.f};
        for (int j = 0; j < DD; j += 4) {
            float rv[8][4];
            #pragma unroll
            for (int r = 0; r < 8; r++) *(float4*)rv[r] = *(const float4*)&rows[r][j];
            #pragma unroll
            for (int k = 0; k < 4; k++) {
                float q = bf2f(qwb[(j + k) * DD + d]);
                #pragma unroll
                for (int r = 0; r < 8; r++) acc[r] += rv[r][k] * q;
            }
        }
        #pragma unroll
        for (int r = 0; r < 8; r++)
            if (base + r < N) qh[(size_t)(base + r) * DD + d] = f2bf(acc[r]);
        __syncthreads();
    }
}

// ------------------- att[e] = qh[head] . tanh((rel*agg[tail]) @ k_w) -------------------
// 64-edge tile per block. X staged f32 transposed [j][e'] (stride 64), k_w bf16 [j][d].
// Thread tile: 4 edges x 8 dims -> 32 fma per j per thread; LDS reads dedup via broadcast.
__global__ void __launch_bounds__(256) k_att(const float* __restrict__ agg,
                                             const float* __restrict__ eemb,
                                             const float* __restrict__ kw,
                                             const u16* __restrict__ qh,
                                             const int* __restrict__ head,
                                             const int* __restrict__ tail,
                                             const int* __restrict__ etype,
                                             int E, float* __restrict__ att) {
    __shared__ float Xs[DD * 64];   // 32 KB: Xs[j*64 + e']
    __shared__ u16 kwb[DD * DD];    // 32 KB: kwb[j*128 + d]
    int tid = threadIdx.x;
    for (int i = tid; i < DD * DD; i += 256) kwb[i] = f2bf(kw[i]);
    int eb = blockIdx.x * 64;
    {   // stage X = rel (*) agg[tail] ; zero-pad invalid edges
        int ep = tid & 63, e = eb + ep;
        int j0 = (tid >> 6) * 32;
        if (e < E) {
            int t = tail[e], r = etype[e];
            const float* ar = agg + (size_t)t * DD;
            const float* rr = eemb + (size_t)r * DD;
            for (int j = j0; j < j0 + 32; j += 4) {
                float4 a = *(const float4*)(ar + j);
                float4 b = *(const float4*)(rr + j);
                Xs[(j + 0) * 64 + ep] = a.x * b.x;
                Xs[(j + 1) * 64 + ep] = a.y * b.y;
                Xs[(j + 2) * 64 + ep] = a.z * b.z;
                Xs[(j + 3) * 64 + ep] = a.w * b.w;
            }
        } else {
            for (int j = j0; j < j0 + 32; ++j) Xs[j * 64 + ep] = 0.f;
        }
    }
    __syncthreads();
    int tx = tid & 15, ty = tid >> 4;     // tx -> dim group, ty -> edge group
    int d0 = tx * 8, e0 = ty * 4;
    float acc[4][8];
    #pragma unroll
    for (int i = 0; i < 4; i++)
        #pragma unroll
        for (int k = 0; k < 8; k++) acc[i][k] = 0.f;
    for (int j = 0; j < DD; j++) {
        float xe[4];
        *(float4*)xe = *(const float4*)&Xs[j * 64 + e0];
        uint4 kv = *(const uint4*)&kwb[j * DD + d0];
        float kd[8];
        kd[0] = bf2f((u16)(kv.x & 0xffffu)); kd[1] = bf2f((u16)(kv.x >> 16));
        kd[2] = bf2f((u16)(kv.y & 0xffffu)); kd[3] = bf2f((u16)(kv.y >> 16));
        kd[4] = bf2f((u16)(kv.z & 0xffffu)); kd[5] = bf2f((u16)(kv.z >> 16));
        kd[6] = bf2f((u16)(kv.w & 0xffffu)); kd[7] = bf2f((u16)(kv.w >> 16));
        #pragma unroll
        for (int i = 0; i < 4; i++)
            #pragma unroll
            for (int k = 0; k < 8; k++) acc[i][k] += xe[i] * kd[k];
    }
    float attp[4];
    #pragma unroll
    for (int i = 0; i < 4; i++) {
        int e = eb + e0 + i;
        float s = 0.f;
        if (e < E) {
            int h = head[e];
            const u16* qr = qh + (size_t)h * DD + d0;
            uint4 qv = *(const uint4*)qr;
            float q[8];
            q[0] = bf2f((u16)(qv.x & 0xffffu)); q[1] = bf2f((u16)(qv.x >> 16));
            q[2] = bf2f((u16)(qv.y & 0xffffu)); q[3] = bf2f((u16)(qv.y >> 16));
            q[4] = bf2f((u16)(qv.z & 0xffffu)); q[5] = bf2f((u16)(qv.z >> 16));
            q[6] = bf2f((u16)(qv.w & 0xffffu)); q[7] = bf2f((u16)(qv.w >> 16));
            #pragma unroll
            for (int k = 0; k < 8; k++) s += q[k] * fast_tanh(acc[i][k]);
        }
        attp[i] = s;
    }
    #pragma unroll
    for (int off = 1; off < 16; off <<= 1) {
        #pragma unroll
        for (int i = 0; i < 4; i++) attp[i] += __shfl_xor(attp[i], off);
    }
    if (tx == 0) {
        #pragma unroll
        for (int i = 0; i < 4; i++) {
            int e = eb + e0 + i;
            if (e < E) att[e] = attp[i];
        }
    }
}

// ------------------- per-node: softmax-weighted gather + normalize + out update ---------
// One wave per node. mode: 0 = out = agg; 1 = out += agg; 2 = out += agg + 3*entity.
__global__ void k_agg(const float* __restrict__ agg, const float* __restrict__ eemb,
                      const float* __restrict__ att, const int* __restrict__ row_off,
                      const int* __restrict__ c_eid, const int* __restrict__ c_tail,
                      const int* __restrict__ c_type, const float* __restrict__ entity,
                      float* __restrict__ agg_next, float* __restrict__ outacc,
                      int N, int mode) {
    int lane = threadIdx.x & 63;
    int n = blockIdx.x * (blockDim.x >> 6) + (threadIdx.x >> 6);
    if (n >= N) return;
    int p0 = row_off[n], p1 = row_off[n + 1];
    float a0 = 0.f, a1 = 0.f;
    if (p1 > p0) {
        float m = -1e30f;
        for (int p = p0; p < p1; p++) m = fmaxf(m, att[c_eid[p]]);
        for (int p = p0; p < p1; p++) {
            float w = __expf(att[c_eid[p]] - m);
            int t = c_tail[p], r = c_type[p];
            float2 av = *(const float2*)(agg + (size_t)t * DD + lane * 2);
            float2 rv = *(const float2*)(eemb + (size_t)r * DD + lane * 2);
            a0 += w * av.x * rv.x;
            a1 += w * av.y * rv.y;
        }
        float s = a0 * a0 + a1 * a1;
        #pragma unroll
        for (int off = 1; off < 64; off <<= 1) s += __shfl_xor(s, off);
        float sc = 1.f / fmaxf(sqrtf(s), 1e-12f);
        a0 *= sc; a1 *= sc;
    }
    size_t idx = (size_t)n * DD + lane * 2;
    agg_next[idx] = a0; agg_next[idx + 1] = a1;
    float o0, o1;
    if (mode == 0) { o0 = a0; o1 = a1; }
    else { o0 = outacc[idx] + a0; o1 = outacc[idx + 1] + a1; }
    if (mode == 2) { o0 += 3.f * entity[idx]; o1 += 3.f * entity[idx + 1]; }
    outacc[idx] = o0; outacc[idx + 1] = o1;
}

extern "C" void kernel_launch(void* const* d_in, const int* in_sizes, int n_in,
                              void* d_out, int out_size, void* d_ws, size_t ws_size,
                              hipStream_t stream) {
    const float* entity = (const float*)d_in[0];
    const float* eemb   = (const float*)d_in[1];
    const float* qw     = (const float*)d_in[2];
    const float* kw     = (const float*)d_in[3];
    const int*   eidx   = (const int*)d_in[4];
    const int*   etype  = (const int*)d_in[5];
    const int N = in_sizes[0] / DD;
    const int E = in_sizes[5];
    const int* head = eidx;
    const int* tail = eidx + E;

    // workspace carve (~139 MB total)
    char* w = (char*)d_ws;
    auto carve = [&](size_t bytes) -> void* {
        void* p = (void*)w;
        w += ((bytes + 255) / 256) * 256;
        return p;
    };
    float* aggA   = (float*)carve((size_t)N * DD * 4);
    float* aggB   = (float*)carve((size_t)N * DD * 4);
    u16*   qh     = (u16*)  carve((size_t)N * DD * 2);
    float* att    = (float*)carve((size_t)E * 4);
    int* counts   = (int*)carve((size_t)N * 4);
    int* row_off  = (int*)carve((size_t)(N + 1) * 4);
    int* cursor   = (int*)carve((size_t)N * 4);
    int* c_eid    = (int*)carve((size_t)E * 4);
    int* c_tail   = (int*)carve((size_t)E * 4);
    int* c_type   = (int*)carve((size_t)E * 4);
    int* partials = (int*)carve(4096);
    (void)ws_size; (void)n_in; (void)out_size;

    hipMemsetAsync(counts, 0, (size_t)N * 4, stream);
    hipMemsetAsync(cursor, 0, (size_t)N * 4, stream);
    k_hist<<<(E + 255) / 256, 256, 0, stream>>>(head, E, counts);
    int nch = (N + 1023) / 1024;
    k_scan_a<<<nch, 1024, 0, stream>>>(counts, N, row_off, partials);
    k_scan_b<<<1, 64, 0, stream>>>(partials, nch);
    k_scan_c<<<nch, 1024, 0, stream>>>(row_off, partials, N, E);
    k_fill<<<(E + 255) / 256, 256, 0, stream>>>(head, tail, etype, E, row_off, cursor,
                                                c_eid, c_tail, c_type);

    const float* cur = entity;
    float* bufs[2] = {aggA, aggB};
    for (int hop = 0; hop < 3; hop++) {
        k_qproj<<<2048, 128, 0, stream>>>(cur, qw, qh, N);
        k_att<<<(E + 63) / 64, 256, 0, stream>>>(cur, eemb, kw, qh, head, tail, etype, E, att);
        float* nxt = bufs[hop & 1];
        int mode = (hop == 0) ? 0 : ((hop == 2) ? 2 : 1);
        k_agg<<<(N + 3) / 4, 256, 0, stream>>>(cur, eemb, att, row_off, c_eid, c_tail, c_type,
                                               entity, nxt, (float*)d_out, N, mode);
        cur = nxt;
    }
}

// Round 3
// 1286.713 us; speedup vs baseline: 1.4854x; 1.4854x over previous
//
#include <hip/hip_runtime.h>

// KG attention, 3 hops.
//  - softmax denom & cnt cancel under L2 normalize: agg_next = normalize(sum_e exp(att-m)*X_e)
//  - qh = agg @ q_w per NODE; CSR by head; edges processed in CSR order
//  - att core: X(bf16,LDS,swizzled) @ kwT(bf16,LDS,swizzled) via mfma_f32_16x16x32_bf16
//  - k_agg gathers X = rel*agg[tail] in f32 via CSR (att already CSR-ordered)
// Workspace ~138.8 MB (round-1-proven size; round-2's 293 MB Xb overflowed d_ws).

#define DD 128

typedef unsigned short u16;
typedef unsigned int u32;
typedef __attribute__((ext_vector_type(8))) __bf16 bf16x8;
typedef __attribute__((ext_vector_type(4))) float f32x4;

__device__ __forceinline__ float bf2f(u16 u) { return __uint_as_float(((u32)u) << 16); }
__device__ __forceinline__ u16 f2bf(float f) {
    u32 u = __float_as_uint(f);
    u += 0x7FFFu + ((u >> 16) & 1u);   // RNE
    return (u16)(u >> 16);
}
__device__ __forceinline__ u32 cvt_pk_bf16(float a, float b) {
    u32 r;
    asm("v_cvt_pk_bf16_f32 %0, %1, %2" : "=v"(r) : "v"(a), "v"(b));
    return r;
}
__device__ __forceinline__ float fast_tanh(float x) {
    // tanh(x) = 1 - 2/(e^{2x}+1); saturates correctly at +-inf
    float e = __builtin_amdgcn_exp2f(x * 2.8853900817779268f);  // e^{2x}
    float r = __builtin_amdgcn_rcpf(e + 1.f);
    return __builtin_fmaf(-2.f, r, 1.f);
}

// ------------------- CSR build (once per call; head is hop-invariant) -------------------
__global__ void k_hist(const int* __restrict__ head, int E, int* __restrict__ counts) {
    int e = blockIdx.x * blockDim.x + threadIdx.x;
    if (e < E) atomicAdd(&counts[head[e]], 1);
}

__global__ void k_scan_a(const int* __restrict__ counts, int N, int* __restrict__ row_off,
                         int* __restrict__ partials) {
    __shared__ int sw[16];
    int i = blockIdx.x * 1024 + threadIdx.x;
    int v = (i < N) ? counts[i] : 0;
    int lane = threadIdx.x & 63, wid = threadIdx.x >> 6;
    int x = v;
    #pragma unroll
    for (int off = 1; off < 64; off <<= 1) {
        int t = __shfl_up(x, off);
        if (lane >= off) x += t;
    }
    if (lane == 63) sw[wid] = x;
    __syncthreads();
    if (threadIdx.x == 0) {
        int run = 0;
        for (int w0 = 0; w0 < 16; w0++) { int t = sw[w0]; sw[w0] = run; run += t; }
        partials[blockIdx.x] = run;
    }
    __syncthreads();
    if (i < N) row_off[i] = x - v + sw[wid];   // chunk-local exclusive
}
__global__ void k_scan_b(int* __restrict__ partials, int nch) {
    if (blockIdx.x == 0 && threadIdx.x == 0) {
        int run = 0;
        for (int c = 0; c < nch; c++) { int t = partials[c]; partials[c] = run; run += t; }
    }
}
__global__ void k_scan_c(int* __restrict__ row_off, const int* __restrict__ partials, int N, int E) {
    int i = blockIdx.x * 1024 + threadIdx.x;
    if (i < N) row_off[i] += partials[blockIdx.x];
    if (i == 0) row_off[N] = E;
}
__global__ void k_fill(const int* __restrict__ head, const int* __restrict__ tail,
                       const int* __restrict__ etype, int E, const int* __restrict__ row_off,
                       int* __restrict__ cursor, int* __restrict__ c_head,
                       int* __restrict__ c_tail, int* __restrict__ c_type) {
    int e = blockIdx.x * blockDim.x + threadIdx.x;
    if (e >= E) return;
    int h = head[e];
    int p = row_off[h] + atomicAdd(&cursor[h], 1);
    c_head[p] = h; c_tail[p] = tail[e]; c_type[p] = etype[e];
}

// ------------------- kwT prep: transposed + XOR-swizzled bf16 image of k_w --------------
__global__ void k_prep(const float* __restrict__ kw, u16* __restrict__ kwT_swz) {
    int idx = blockIdx.x * 256 + threadIdx.x;
    if (idx >= DD * DD) return;
    int n = idx >> 7, k = idx & 127;
    float v = kw[k * DD + n];
    int byte = (n * 256 + k * 2) ^ ((n & 7) << 4);
    kwT_swz[byte >> 1] = f2bf(v);
}

// ------------------- qh = agg @ q_w  (bf16 out), 8-node register tile -------------------
__global__ void __launch_bounds__(128) k_qproj(const float* __restrict__ agg,
                                               const float* __restrict__ qw,
                                               u16* __restrict__ qh, int N) {
    __shared__ u16 qwb[DD * DD];       // [j][d] bf16, 32 KB
    __shared__ float rows[8][DD];      // 8 staged agg rows, 4 KB
    for (int i = threadIdx.x; i < DD * DD; i += 128) qwb[i] = f2bf(qw[i]);
    __syncthreads();
    int nch = (N + 7) / 8;
    for (int c = blockIdx.x; c < nch; c += gridDim.x) {
        int base = c * 8;
        for (int t = threadIdx.x; t < 8 * DD; t += 128) {
            int idx = base * DD + t;
            rows[t >> 7][t & 127] = (idx < N * DD) ? agg[idx] : 0.f;
        }
        __syncthreads();
        int d = threadIdx.x;
        float acc[8] = {0.f, 0.f, 0.f, 0.f, 0.f, 0.f, 0.f, 0.f};
        for (int j = 0; j < DD; j += 4) {
            float rv[8][4];
            #pragma unroll
            for (int r = 0; r < 8; r++) *(float4*)rv[r] = *(const float4*)&rows[r][j];
            #pragma unroll
            for (int k = 0; k < 4; k++) {
                float q = bf2f(qwb[(j + k) * DD + d]);
                #pragma unroll
                for (int r = 0; r < 8; r++) acc[r] += rv[r][k] * q;
            }
        }
        #pragma unroll
        for (int r = 0; r < 8; r++)
            if (base + r < N) qh[(size_t)(base + r) * DD + d] = f2bf(acc[r]);
        __syncthreads();
    }
}

// ------------------- att[p] = qh[head_p] . tanh(X_p @ k_w) ------------------------------
// 128 CSR positions per block, 4 waves; each wave: 32 edges via 16x16x32 MFMA.
// LDS: sX[128][128] bf16 (swizzled), sKw = kwT swizzled. 64 KB total.
__global__ void __launch_bounds__(256) k_att(const float* __restrict__ agg,
                                             const float* __restrict__ eemb,
                                             const uint4* __restrict__ kwT_swz,
                                             const u16* __restrict__ qh,
                                             const int* __restrict__ c_head,
                                             const int* __restrict__ c_tail,
                                             const int* __restrict__ c_type,
                                             int E, float* __restrict__ att) {
    __shared__ u16 sX[DD * DD];    // 32 KB
    __shared__ u16 sKw[DD * DD];   // 32 KB
    int tid = threadIdx.x;
    // --- stage kwT (linear copy of pre-swizzled image) ---
    {
        uint4* dst = (uint4*)sKw;
        #pragma unroll
        for (int i = 0; i < 8; ++i) dst[i * 256 + tid] = kwT_swz[i * 256 + tid];
    }
    // --- stage X = rel (*) agg[tail] in bf16, swizzled ---
    long pbase = (long)blockIdx.x * 128;
    int qq = tid & 3, er = tid >> 2;        // 4 threads/edge, 32 dims each
    #pragma unroll
    for (int pass = 0; pass < 2; ++pass) {
        int eloc = pass * 64 + er;
        long p = pbase + eloc;
        int d0 = qq * 32;
        __align__(16) u32 pk[16];
        if (p < E) {
            int tl = c_tail[p], rl = c_type[p];
            const float* ar = agg + (size_t)tl * DD + d0;
            const float* rr = eemb + (size_t)rl * DD + d0;
            #pragma unroll
            for (int j = 0; j < 32; j += 4) {
                float4 a = *(const float4*)(ar + j);
                float4 b = *(const float4*)(rr + j);
                pk[(j >> 1) + 0] = cvt_pk_bf16(a.x * b.x, a.y * b.y);
                pk[(j >> 1) + 1] = cvt_pk_bf16(a.z * b.z, a.w * b.w);
            }
        } else {
            #pragma unroll
            for (int i = 0; i < 16; ++i) pk[i] = 0u;
        }
        char* base = (char*)sX;
        #pragma unroll
        for (int c = 0; c < 4; ++c) {
            int byte = (eloc * 256 + d0 * 2 + c * 16) ^ ((eloc & 7) << 4);
            *(uint4*)(base + byte) = *(const uint4*)&pk[c * 4];
        }
    }
    __syncthreads();
    // --- MFMA: S = X @ kwT^T  (A rows = edges, B cols = d) ---
    int lane = tid & 63, wid = tid >> 6;
    int lr = lane & 15, lg = lane >> 4;
    int egbase = wid * 32;                 // wave owns 32 edges (2 groups of 16)
    f32x4 acc[2][8];
    #pragma unroll
    for (int g = 0; g < 2; ++g)
        #pragma unroll
        for (int t = 0; t < 8; ++t) acc[g][t] = (f32x4){0.f, 0.f, 0.f, 0.f};
    const char* xb_ = (const char*)sX;
    const char* kb_ = (const char*)sKw;
    int sw = (lr & 7) << 4;                // row&7 == lr&7 for all A rows and B cols here
    #pragma unroll
    for (int kc = 0; kc < 4; ++kc) {
        int koffb = kc * 64 + lg * 16;
        int r0 = egbase + lr;
        bf16x8 a0 = *(const bf16x8*)(xb_ + ((r0 * 256 + koffb) ^ sw));
        bf16x8 a1 = *(const bf16x8*)(xb_ + (((r0 + 16) * 256 + koffb) ^ sw));
        #pragma unroll
        for (int t = 0; t < 8; ++t) {
            int n = t * 16 + lr;
            bf16x8 b = *(const bf16x8*)(kb_ + ((n * 256 + koffb) ^ sw));
            acc[0][t] = __builtin_amdgcn_mfma_f32_16x16x32_bf16(a0, b, acc[0][t], 0, 0, 0);
            acc[1][t] = __builtin_amdgcn_mfma_f32_16x16x32_bf16(a1, b, acc[1][t], 0, 0, 0);
        }
    }
    // --- tanh + dot with qh[head]; C/D layout: col = lane&15, row = (lane>>4)*4 + reg ---
    float attv[8];
    #pragma unroll
    for (int g = 0; g < 2; ++g) {
        #pragma unroll
        for (int r = 0; r < 4; ++r) {
            int eloc = egbase + g * 16 + lg * 4 + r;
            long p = pbase + eloc;
            int h = (p < E) ? c_head[p] : 0;
            const u16* qrow = qh + (size_t)h * DD + lr;
            float s = 0.f;
            #pragma unroll
            for (int t = 0; t < 8; ++t)
                s += fast_tanh(acc[g][t][r]) * bf2f(qrow[t * 16]);
            attv[g * 4 + r] = s;
        }
    }
    #pragma unroll
    for (int off = 1; off < 16; off <<= 1) {
        #pragma unroll
        for (int i = 0; i < 8; ++i) attv[i] += __shfl_xor(attv[i], off);
    }
    if (lr == 0) {
        #pragma unroll
        for (int g = 0; g < 2; ++g)
            #pragma unroll
            for (int r = 0; r < 4; ++r) {
                long p = pbase + egbase + g * 16 + lg * 4 + r;
                if (p < E) att[p] = attv[g * 4 + r];
            }
    }
}

// ------------------- per-node: softmax-weighted gather + normalize + out update ---------
// One wave per node; att/c_tail/c_type in CSR order -> sequential index reads, random agg rows.
__global__ void k_agg(const float* __restrict__ agg, const float* __restrict__ eemb,
                      const float* __restrict__ att, const int* __restrict__ row_off,
                      const int* __restrict__ c_tail, const int* __restrict__ c_type,
                      const float* __restrict__ entity,
                      float* __restrict__ agg_next, float* __restrict__ outacc,
                      int N, int mode) {
    int lane = threadIdx.x & 63;
    int n = blockIdx.x * (blockDim.x >> 6) + (threadIdx.x >> 6);
    if (n >= N) return;
    int p0 = row_off[n], p1 = row_off[n + 1];
    float a0 = 0.f, a1 = 0.f;
    if (p1 > p0) {
        float m = -1e30f;
        for (int p = p0; p < p1; p++) m = fmaxf(m, att[p]);
        for (int p = p0; p < p1; p++) {
            float w = __expf(att[p] - m);
            int t = c_tail[p], r = c_type[p];
            float2 av = *(const float2*)(agg + (size_t)t * DD + lane * 2);
            float2 rv = *(const float2*)(eemb + (size_t)r * DD + lane * 2);
            a0 += w * av.x * rv.x;
            a1 += w * av.y * rv.y;
        }
        float s = a0 * a0 + a1 * a1;
        #pragma unroll
        for (int off = 1; off < 64; off <<= 1) s += __shfl_xor(s, off);
        float sc = 1.f / fmaxf(sqrtf(s), 1e-12f);
        a0 *= sc; a1 *= sc;
    }
    size_t idx = (size_t)n * DD + lane * 2;
    agg_next[idx] = a0; agg_next[idx + 1] = a1;
    float o0, o1;
    if (mode == 0) { o0 = a0; o1 = a1; }
    else { o0 = outacc[idx] + a0; o1 = outacc[idx + 1] + a1; }
    if (mode == 2) { o0 += 3.f * entity[idx]; o1 += 3.f * entity[idx + 1]; }
    outacc[idx] = o0; outacc[idx + 1] = o1;
}

extern "C" void kernel_launch(void* const* d_in, const int* in_sizes, int n_in,
                              void* d_out, int out_size, void* d_ws, size_t ws_size,
                              hipStream_t stream) {
    const float* entity = (const float*)d_in[0];
    const float* eemb   = (const float*)d_in[1];
    const float* qw     = (const float*)d_in[2];
    const float* kw     = (const float*)d_in[3];
    const int*   eidx   = (const int*)d_in[4];
    const int*   etype  = (const int*)d_in[5];
    const int N = in_sizes[0] / DD;
    const int E = in_sizes[5];
    const int* head = eidx;
    const int* tail = eidx + E;

    // workspace carve (~138.8 MB)
    char* w = (char*)d_ws;
    auto carve = [&](size_t bytes) -> void* {
        void* p = (void*)w;
        w += ((bytes + 255) / 256) * 256;
        return p;
    };
    float* aggA    = (float*)carve((size_t)N * DD * 4);
    float* aggB    = (float*)carve((size_t)N * DD * 4);
    u16*   qh      = (u16*)  carve((size_t)N * DD * 2);
    float* att     = (float*)carve((size_t)E * 4);
    int* counts    = (int*)carve((size_t)N * 4);
    int* row_off   = (int*)carve((size_t)(N + 1) * 4);
    int* cursor    = (int*)carve((size_t)N * 4);
    int* c_head    = (int*)carve((size_t)E * 4);
    int* c_tail    = (int*)carve((size_t)E * 4);
    int* c_type    = (int*)carve((size_t)E * 4);
    u16* kwT_swz   = (u16*)carve((size_t)DD * DD * 2);
    int* partials  = (int*)carve(4096);
    (void)ws_size; (void)n_in; (void)out_size;

    hipMemsetAsync(counts, 0, (size_t)N * 4, stream);
    hipMemsetAsync(cursor, 0, (size_t)N * 4, stream);
    k_prep<<<(DD * DD + 255) / 256, 256, 0, stream>>>(kw, kwT_swz);
    k_hist<<<(E + 255) / 256, 256, 0, stream>>>(head, E, counts);
    int nch = (N + 1023) / 1024;
    k_scan_a<<<nch, 1024, 0, stream>>>(counts, N, row_off, partials);
    k_scan_b<<<1, 64, 0, stream>>>(partials, nch);
    k_scan_c<<<nch, 1024, 0, stream>>>(row_off, partials, N, E);
    k_fill<<<(E + 255) / 256, 256, 0, stream>>>(head, tail, etype, E, row_off, cursor,
                                                c_head, c_tail, c_type);

    const float* cur = entity;
    float* bufs[2] = {aggA, aggB};
    for (int hop = 0; hop < 3; hop++) {
        k_qproj<<<2048, 128, 0, stream>>>(cur, qw, qh, N);
        k_att<<<(E + 127) / 128, 256, 0, stream>>>(cur, eemb, (const uint4*)kwT_swz, qh,
                                                   c_head, c_tail, c_type, E, att);
        float* nxt = bufs[hop & 1];
        int mode = (hop == 0) ? 0 : ((hop == 2) ? 2 : 1);
        k_agg<<<(N + 3) / 4, 256, 0, stream>>>(cur, eemb, att, row_off, c_tail, c_type,
                                               entity, nxt, (float*)d_out, N, mode);
        cur = nxt;
    }
}

// Round 4
// 900.920 us; speedup vs baseline: 2.1215x; 1.4282x over previous
//
#include <hip/hip_runtime.h>

// KG attention, 3 hops.
//  - softmax denom & cnt cancel under L2 normalize: agg_next = normalize(sum_e exp(att-m)*X_e)
//  - qh = agg @ q_w per NODE via MFMA; CSR by head; edges processed in CSR order
//  - att core: X(bf16,LDS,swizzled) @ kwT(bf16,LDS,swizzled) via mfma_f32_16x16x32_bf16
//  - k_agg gathers X = rel*agg[tail] in f32 via CSR (att already CSR-ordered)
// Workspace ~138.9 MB (round-1-proven size).

#define DD 128

typedef unsigned short u16;
typedef unsigned int u32;
typedef __attribute__((ext_vector_type(8))) __bf16 bf16x8;
typedef __attribute__((ext_vector_type(4))) float f32x4;

__device__ __forceinline__ float bf2f(u16 u) { return __uint_as_float(((u32)u) << 16); }
__device__ __forceinline__ u16 f2bf(float f) {
    u32 u = __float_as_uint(f);
    u += 0x7FFFu + ((u >> 16) & 1u);   // RNE
    return (u16)(u >> 16);
}
__device__ __forceinline__ u32 cvt_pk_bf16(float a, float b) {
    u32 r;
    asm("v_cvt_pk_bf16_f32 %0, %1, %2" : "=v"(r) : "v"(a), "v"(b));
    return r;
}
__device__ __forceinline__ float fast_tanh(float x) {
    // tanh(x) = 1 - 2/(e^{2x}+1); saturates correctly at +-inf
    float e = __builtin_amdgcn_exp2f(x * 2.8853900817779268f);  // e^{2x}
    float r = __builtin_amdgcn_rcpf(e + 1.f);
    return __builtin_fmaf(-2.f, r, 1.f);
}

// ------------------- CSR build (once per call; head is hop-invariant) -------------------
__global__ void k_hist(const int* __restrict__ head, int E, int* __restrict__ counts) {
    int e = blockIdx.x * blockDim.x + threadIdx.x;
    if (e < E) atomicAdd(&counts[head[e]], 1);
}

__global__ void k_scan_a(const int* __restrict__ counts, int N, int* __restrict__ row_off,
                         int* __restrict__ partials) {
    __shared__ int sw[16];
    int i = blockIdx.x * 1024 + threadIdx.x;
    int v = (i < N) ? counts[i] : 0;
    int lane = threadIdx.x & 63, wid = threadIdx.x >> 6;
    int x = v;
    #pragma unroll
    for (int off = 1; off < 64; off <<= 1) {
        int t = __shfl_up(x, off);
        if (lane >= off) x += t;
    }
    if (lane == 63) sw[wid] = x;
    __syncthreads();
    if (threadIdx.x == 0) {
        int run = 0;
        for (int w0 = 0; w0 < 16; w0++) { int t = sw[w0]; sw[w0] = run; run += t; }
        partials[blockIdx.x] = run;
    }
    __syncthreads();
    if (i < N) row_off[i] = x - v + sw[wid];   // chunk-local exclusive
}
__global__ void k_scan_b(int* __restrict__ partials, int nch) {
    if (blockIdx.x == 0 && threadIdx.x == 0) {
        int run = 0;
        for (int c = 0; c < nch; c++) { int t = partials[c]; partials[c] = run; run += t; }
    }
}
__global__ void k_scan_c(int* __restrict__ row_off, const int* __restrict__ partials, int N, int E) {
    int i = blockIdx.x * 1024 + threadIdx.x;
    if (i < N) row_off[i] += partials[blockIdx.x];
    if (i == 0) row_off[N] = E;
}
__global__ void k_fill(const int* __restrict__ head, const int* __restrict__ tail,
                       const int* __restrict__ etype, int E, const int* __restrict__ row_off,
                       int* __restrict__ cursor, int* __restrict__ c_head,
                       int* __restrict__ c_tail, int* __restrict__ c_type) {
    int e = blockIdx.x * blockDim.x + threadIdx.x;
    if (e >= E) return;
    int h = head[e];
    int p = row_off[h] + atomicAdd(&cursor[h], 1);
    c_head[p] = h; c_tail[p] = tail[e]; c_type[p] = etype[e];
}

// ------------------- weight prep: transposed + XOR-swizzled bf16 image ------------------
// dst_swz[(n*256 + k*2)^((n&7)<<4) >> 1] = bf16(src[k][n]); LDS-linear copy + swizzled
// ds_read yields W^T[n][k].
__global__ void k_prep(const float* __restrict__ src, u16* __restrict__ dst_swz) {
    int idx = blockIdx.x * 256 + threadIdx.x;
    if (idx >= DD * DD) return;
    int n = idx >> 7, k = idx & 127;
    float v = src[k * DD + n];
    int byte = (n * 256 + k * 2) ^ ((n & 7) << 4);
    dst_swz[byte >> 1] = f2bf(v);
}

// ------------------- qh = agg @ q_w  (bf16 out) via MFMA --------------------------------
// 128 rows per block, 4 waves; identical structure to k_att's GEMM core.
__global__ void __launch_bounds__(256) k_qproj(const float* __restrict__ agg,
                                               const uint4* __restrict__ qwT_swz,
                                               u16* __restrict__ qh, int N) {
    __shared__ u16 sA[DD * DD];    // 32 KB, swizzled bf16 agg rows
    __shared__ u16 sB[DD * DD];    // 32 KB, qwT swizzled
    int tid = threadIdx.x;
    {
        uint4* dst = (uint4*)sB;
        #pragma unroll
        for (int i = 0; i < 8; ++i) dst[i * 256 + tid] = qwT_swz[i * 256 + tid];
    }
    long base = (long)blockIdx.x * 128;
    int qq = tid & 3, er = tid >> 2;        // 4 threads/row, 32 dims each
    #pragma unroll
    for (int pass = 0; pass < 2; ++pass) {
        int rloc = pass * 64 + er;
        long n = base + rloc;
        int d0 = qq * 32;
        __align__(16) u32 pk[16];
        if (n < N) {
            const float* ar = agg + (size_t)n * DD + d0;
            #pragma unroll
            for (int j = 0; j < 32; j += 4) {
                float4 a = *(const float4*)(ar + j);
                pk[(j >> 1) + 0] = cvt_pk_bf16(a.x, a.y);
                pk[(j >> 1) + 1] = cvt_pk_bf16(a.z, a.w);
            }
        } else {
            #pragma unroll
            for (int i = 0; i < 16; ++i) pk[i] = 0u;
        }
        char* basep = (char*)sA;
        #pragma unroll
        for (int c = 0; c < 4; ++c) {
            int byte = (rloc * 256 + d0 * 2 + c * 16) ^ ((rloc & 7) << 4);
            *(uint4*)(basep + byte) = *(const uint4*)&pk[c * 4];
        }
    }
    __syncthreads();
    int lane = tid & 63, wid = tid >> 6;
    int lr = lane & 15, lg = lane >> 4;
    int rgbase = wid * 32;                 // wave owns 32 rows (2 groups of 16)
    f32x4 acc[2][8];
    #pragma unroll
    for (int g = 0; g < 2; ++g)
        #pragma unroll
        for (int t = 0; t < 8; ++t) acc[g][t] = (f32x4){0.f, 0.f, 0.f, 0.f};
    const char* ab_ = (const char*)sA;
    const char* bb_ = (const char*)sB;
    int sw = (lr & 7) << 4;
    #pragma unroll
    for (int kc = 0; kc < 4; ++kc) {
        int koffb = kc * 64 + lg * 16;
        int r0 = rgbase + lr;
        bf16x8 a0 = *(const bf16x8*)(ab_ + ((r0 * 256 + koffb) ^ sw));
        bf16x8 a1 = *(const bf16x8*)(ab_ + (((r0 + 16) * 256 + koffb) ^ sw));
        #pragma unroll
        for (int t = 0; t < 8; ++t) {
            int n = t * 16 + lr;
            bf16x8 b = *(const bf16x8*)(bb_ + ((n * 256 + koffb) ^ sw));
            acc[0][t] = __builtin_amdgcn_mfma_f32_16x16x32_bf16(a0, b, acc[0][t], 0, 0, 0);
            acc[1][t] = __builtin_amdgcn_mfma_f32_16x16x32_bf16(a1, b, acc[1][t], 0, 0, 0);
        }
    }
    // C/D: col = t*16 + (lane&15), row = rgbase + g*16 + (lane>>4)*4 + r
    #pragma unroll
    for (int g = 0; g < 2; ++g)
        #pragma unroll
        for (int r = 0; r < 4; ++r) {
            long row = base + rgbase + g * 16 + lg * 4 + r;
            if (row < N) {
                u16* qrow = qh + (size_t)row * DD + lr;
                #pragma unroll
                for (int t = 0; t < 8; ++t) qrow[t * 16] = f2bf(acc[g][t][r]);
            }
        }
}

// ------------------- att[p] = qh[head_p] . tanh(X_p @ k_w) ------------------------------
// 128 CSR positions per block, 4 waves; each wave: 32 edges via 16x16x32 MFMA.
__global__ void __launch_bounds__(256) k_att(const float* __restrict__ agg,
                                             const float* __restrict__ eemb,
                                             const uint4* __restrict__ kwT_swz,
                                             const u16* __restrict__ qh,
                                             const int* __restrict__ c_head,
                                             const int* __restrict__ c_tail,
                                             const int* __restrict__ c_type,
                                             int E, float* __restrict__ att) {
    __shared__ u16 sX[DD * DD];    // 32 KB
    __shared__ u16 sKw[DD * DD];   // 32 KB
    int tid = threadIdx.x;
    {
        uint4* dst = (uint4*)sKw;
        #pragma unroll
        for (int i = 0; i < 8; ++i) dst[i * 256 + tid] = kwT_swz[i * 256 + tid];
    }
    long pbase = (long)blockIdx.x * 128;
    int qq = tid & 3, er = tid >> 2;        // 4 threads/edge, 32 dims each
    #pragma unroll
    for (int pass = 0; pass < 2; ++pass) {
        int eloc = pass * 64 + er;
        long p = pbase + eloc;
        int d0 = qq * 32;
        __align__(16) u32 pk[16];
        if (p < E) {
            int tl = c_tail[p], rl = c_type[p];
            const float* ar = agg + (size_t)tl * DD + d0;
            const float* rr = eemb + (size_t)rl * DD + d0;
            #pragma unroll
            for (int j = 0; j < 32; j += 4) {
                float4 a = *(const float4*)(ar + j);
                float4 b = *(const float4*)(rr + j);
                pk[(j >> 1) + 0] = cvt_pk_bf16(a.x * b.x, a.y * b.y);
                pk[(j >> 1) + 1] = cvt_pk_bf16(a.z * b.z, a.w * b.w);
            }
        } else {
            #pragma unroll
            for (int i = 0; i < 16; ++i) pk[i] = 0u;
        }
        char* base = (char*)sX;
        #pragma unroll
        for (int c = 0; c < 4; ++c) {
            int byte = (eloc * 256 + d0 * 2 + c * 16) ^ ((eloc & 7) << 4);
            *(uint4*)(base + byte) = *(const uint4*)&pk[c * 4];
        }
    }
    __syncthreads();
    int lane = tid & 63, wid = tid >> 6;
    int lr = lane & 15, lg = lane >> 4;
    int egbase = wid * 32;                 // wave owns 32 edges (2 groups of 16)
    f32x4 acc[2][8];
    #pragma unroll
    for (int g = 0; g < 2; ++g)
        #pragma unroll
        for (int t = 0; t < 8; ++t) acc[g][t] = (f32x4){0.f, 0.f, 0.f, 0.f};
    const char* xb_ = (const char*)sX;
    const char* kb_ = (const char*)sKw;
    int sw = (lr & 7) << 4;
    #pragma unroll
    for (int kc = 0; kc < 4; ++kc) {
        int koffb = kc * 64 + lg * 16;
        int r0 = egbase + lr;
        bf16x8 a0 = *(const bf16x8*)(xb_ + ((r0 * 256 + koffb) ^ sw));
        bf16x8 a1 = *(const bf16x8*)(xb_ + (((r0 + 16) * 256 + koffb) ^ sw));
        #pragma unroll
        for (int t = 0; t < 8; ++t) {
            int n = t * 16 + lr;
            bf16x8 b = *(const bf16x8*)(kb_ + ((n * 256 + koffb) ^ sw));
            acc[0][t] = __builtin_amdgcn_mfma_f32_16x16x32_bf16(a0, b, acc[0][t], 0, 0, 0);
            acc[1][t] = __builtin_amdgcn_mfma_f32_16x16x32_bf16(a1, b, acc[1][t], 0, 0, 0);
        }
    }
    // tanh + dot with qh[head]; C/D: col = lane&15, row = (lane>>4)*4 + reg
    float attv[8];
    #pragma unroll
    for (int g = 0; g < 2; ++g) {
        #pragma unroll
        for (int r = 0; r < 4; ++r) {
            int eloc = egbase + g * 16 + lg * 4 + r;
            long p = pbase + eloc;
            int h = (p < E) ? c_head[p] : 0;
            const u16* qrow = qh + (size_t)h * DD + lr;
            float s = 0.f;
            #pragma unroll
            for (int t = 0; t < 8; ++t)
                s += fast_tanh(acc[g][t][r]) * bf2f(qrow[t * 16]);
            attv[g * 4 + r] = s;
        }
    }
    #pragma unroll
    for (int off = 1; off < 16; off <<= 1) {
        #pragma unroll
        for (int i = 0; i < 8; ++i) attv[i] += __shfl_xor(attv[i], off);
    }
    if (lr == 0) {
        #pragma unroll
        for (int g = 0; g < 2; ++g)
            #pragma unroll
            for (int r = 0; r < 4; ++r) {
                long p = pbase + egbase + g * 16 + lg * 4 + r;
                if (p < E) att[p] = attv[g * 4 + r];
            }
    }
}

// ------------------- per-node: softmax-weighted gather + normalize + out update ---------
__global__ void k_agg(const float* __restrict__ agg, const float* __restrict__ eemb,
                      const float* __restrict__ att, const int* __restrict__ row_off,
                      const int* __restrict__ c_tail, const int* __restrict__ c_type,
                      const float* __restrict__ entity,
                      float* __restrict__ agg_next, float* __restrict__ outacc,
                      int N, int mode) {
    int lane = threadIdx.x & 63;
    int n = blockIdx.x * (blockDim.x >> 6) + (threadIdx.x >> 6);
    if (n >= N) return;
    int p0 = row_off[n], p1 = row_off[n + 1];
    float a0 = 0.f, a1 = 0.f;
    if (p1 > p0) {
        float m = -1e30f;
        for (int p = p0; p < p1; p++) m = fmaxf(m, att[p]);
        for (int p = p0; p < p1; p++) {
            float w = __expf(att[p] - m);
            int t = c_tail[p], r = c_type[p];
            float2 av = *(const float2*)(agg + (size_t)t * DD + lane * 2);
            float2 rv = *(const float2*)(eemb + (size_t)r * DD + lane * 2);
            a0 += w * av.x * rv.x;
            a1 += w * av.y * rv.y;
        }
        float s = a0 * a0 + a1 * a1;
        #pragma unroll
        for (int off = 1; off < 64; off <<= 1) s += __shfl_xor(s, off);
        float sc = 1.f / fmaxf(sqrtf(s), 1e-12f);
        a0 *= sc; a1 *= sc;
    }
    size_t idx = (size_t)n * DD + lane * 2;
    agg_next[idx] = a0; agg_next[idx + 1] = a1;
    float o0, o1;
    if (mode == 0) { o0 = a0; o1 = a1; }
    else { o0 = outacc[idx] + a0; o1 = outacc[idx + 1] + a1; }
    if (mode == 2) { o0 += 3.f * entity[idx]; o1 += 3.f * entity[idx + 1]; }
    outacc[idx] = o0; outacc[idx + 1] = o1;
}

extern "C" void kernel_launch(void* const* d_in, const int* in_sizes, int n_in,
                              void* d_out, int out_size, void* d_ws, size_t ws_size,
                              hipStream_t stream) {
    const float* entity = (const float*)d_in[0];
    const float* eemb   = (const float*)d_in[1];
    const float* qw     = (const float*)d_in[2];
    const float* kw     = (const float*)d_in[3];
    const int*   eidx   = (const int*)d_in[4];
    const int*   etype  = (const int*)d_in[5];
    const int N = in_sizes[0] / DD;
    const int E = in_sizes[5];
    const int* head = eidx;
    const int* tail = eidx + E;

    // workspace carve (~138.9 MB)
    char* w = (char*)d_ws;
    auto carve = [&](size_t bytes) -> void* {
        void* p = (void*)w;
        w += ((bytes + 255) / 256) * 256;
        return p;
    };
    float* aggA    = (float*)carve((size_t)N * DD * 4);
    float* aggB    = (float*)carve((size_t)N * DD * 4);
    u16*   qh      = (u16*)  carve((size_t)N * DD * 2);
    float* att     = (float*)carve((size_t)E * 4);
    int* counts    = (int*)carve((size_t)N * 4);
    int* row_off   = (int*)carve((size_t)(N + 1) * 4);
    int* cursor    = (int*)carve((size_t)N * 4);
    int* c_head    = (int*)carve((size_t)E * 4);
    int* c_tail    = (int*)carve((size_t)E * 4);
    int* c_type    = (int*)carve((size_t)E * 4);
    u16* kwT_swz   = (u16*)carve((size_t)DD * DD * 2);
    u16* qwT_swz   = (u16*)carve((size_t)DD * DD * 2);
    int* partials  = (int*)carve(4096);
    (void)ws_size; (void)n_in; (void)out_size;

    hipMemsetAsync(counts, 0, (size_t)N * 4, stream);
    hipMemsetAsync(cursor, 0, (size_t)N * 4, stream);
    k_prep<<<(DD * DD + 255) / 256, 256, 0, stream>>>(kw, kwT_swz);
    k_prep<<<(DD * DD + 255) / 256, 256, 0, stream>>>(qw, qwT_swz);
    k_hist<<<(E + 255) / 256, 256, 0, stream>>>(head, E, counts);
    int nch = (N + 1023) / 1024;
    k_scan_a<<<nch, 1024, 0, stream>>>(counts, N, row_off, partials);
    k_scan_b<<<1, 64, 0, stream>>>(partials, nch);
    k_scan_c<<<nch, 1024, 0, stream>>>(row_off, partials, N, E);
    k_fill<<<(E + 255) / 256, 256, 0, stream>>>(head, tail, etype, E, row_off, cursor,
                                                c_head, c_tail, c_type);

    const float* cur = entity;
    float* bufs[2] = {aggA, aggB};
    for (int hop = 0; hop < 3; hop++) {
        k_qproj<<<(N + 127) / 128, 256, 0, stream>>>(cur, (const uint4*)qwT_swz, qh, N);
        k_att<<<(E + 127) / 128, 256, 0, stream>>>(cur, eemb, (const uint4*)kwT_swz, qh,
                                                   c_head, c_tail, c_type, E, att);
        float* nxt = bufs[hop & 1];
        int mode = (hop == 0) ? 0 : ((hop == 2) ? 2 : 1);
        k_agg<<<(N + 3) / 4, 256, 0, stream>>>(cur, eemb, att, row_off, c_tail, c_type,
                                               entity, nxt, (float*)d_out, N, mode);
        cur = nxt;
    }
}